// Round 17
// baseline (83.324 us; speedup 1.0000x reference)
//
#include <hip/hip_runtime.h>
#include <hip/hip_bf16.h>

// Single causal attention head. B=4, T=4096, C=1024, H=64, fp32 in/out.
// R16 = R14 (best, 71.05us) + finer split-K (S=2, nslots=32 -> 1088 active
// flash blocks) + bf16 partial-O (same total pO bytes at 2x chunks; combine
// reads halve). Flash/qkv/wt bodies are R14-verbatim.

#define B_DIM 4
#define T_DIM 4096
#define C_DIM 1024
#define H_DIM 64
#define SCALE2 0.0450842066f  // log2(e)/32 : base-2 domain folded into q
#define KP 72                 // LDS stride (elems): 144B rows, 16B-aligned

typedef __attribute__((ext_vector_type(8))) short bf8;      // 8 bf16
typedef __attribute__((ext_vector_type(4))) short bf4;      // 4 bf16 (8B)
typedef __attribute__((ext_vector_type(4))) float f32x4;    // 16x16 acc
typedef __attribute__((ext_vector_type(16))) float f32x16;  // 32x32 acc

__device__ __forceinline__ float fast_exp2(float f) {
    return __builtin_amdgcn_exp2f(f);   // v_exp_f32 (base-2)
}
__device__ __forceinline__ ushort f2bf(float f) {
    union { float f; uint u; } x; x.f = f;
    const uint u = x.u;
    return (ushort)((u + 0x7FFFu + ((u >> 16) & 1u)) >> 16);  // RNE
}
__device__ __forceinline__ float bf2f(ushort h) {
    union { uint u; float f; } x; x.u = ((uint)h) << 16;
    return x.f;
}
__device__ __forceinline__ uint cvt_pk_bf16(float lo, float hi) {
    uint r;
    asm("v_cvt_pk_bf16_f32 %0, %1, %2" : "=v"(r) : "v"(lo), "v"(hi));
    return r;
}
__device__ __forceinline__ void permswapf(float& a, float& b) {
    asm volatile("v_permlane32_swap_b32 %0, %1" : "+v"(a), "+v"(b));
}
__device__ __forceinline__ void permswapu(uint& a, uint& b) {
    asm volatile("v_permlane32_swap_b32 %0, %1" : "+v"(a), "+v"(b));
}
__device__ __forceinline__ bf8 frag_from(uint w0, uint w1, uint w2, uint w3) {
    union { uint u[4]; bf8 f; } x;
    x.u[0] = w0; x.u[1] = w1; x.u[2] = w2; x.u[3] = w3;
    return x.f;
}

// ---------------------------------------------------------------------------
// W^T pre-pass: wtg[col][k], col 0..191 = (Wq|Wk|Wv) columns, bf16.
// ---------------------------------------------------------------------------
__global__ __launch_bounds__(256) void wt_kernel(
    const float* __restrict__ Wq, const float* __restrict__ Wk,
    const float* __restrict__ Wv, ushort* __restrict__ wtg)
{
    const int id  = blockIdx.x * 256 + threadIdx.x;  // 24576 total
    const int col = id >> 7;
    const int k8  = (id & 127) * 8;
    const int m   = col >> 6, lc = col & 63;
    const float* W = (m == 0) ? Wq : (m == 1) ? Wk : Wv;
    ushort o[8];
    #pragma unroll
    for (int i = 0; i < 8; ++i)
        o[i] = f2bf(W[(size_t)(k8 + i) * H_DIM + lc]);
    *(bf8*)&wtg[(size_t)col * C_DIM + k8] = *(bf8*)o;
}

// ---------------------------------------------------------------------------
// QKV projection (R6 verbatim). Block = 32 rows x 192 cols, 4 waves x 3
// col-subtiles; K-chunks of 64 with reg-prefetch. Grid 512.
// ---------------------------------------------------------------------------
__global__ __launch_bounds__(256) void qkv_mfma_kernel(
    const float* __restrict__ x, const ushort* __restrict__ wtg,
    ushort* __restrict__ qo, ushort* __restrict__ ko, ushort* __restrict__ vo)
{
    __shared__ ushort xs[32][KP];
    __shared__ ushort wts[192][KP];
    const int t    = threadIdx.x;
    const int lane = t & 63, wave = t >> 6;
    const int g    = lane >> 4, lid = lane & 15;
    const size_t r0 = (size_t)blockIdx.x * 32;

    f32x4 acc[2][3] = {};

    const int xrow = t >> 3, xcol = (t & 7) * 8;   // x stage: 32x64
    float4 xr[2];
    bf8 wreg[6];

    xr[0] = *(const float4*)&x[(r0 + xrow) * C_DIM + xcol];
    xr[1] = *(const float4*)&x[(r0 + xrow) * C_DIM + xcol + 4];
    #pragma unroll
    for (int it = 0; it < 6; ++it) {
        const int n = t + it * 256;
        wreg[it] = *(const bf8*)&wtg[(size_t)(n >> 3) * C_DIM + (n & 7) * 8];
    }

    for (int kc = 0; kc < C_DIM / 64; ++kc) {
        __syncthreads();
        {
            uint p[4];
            p[0] = cvt_pk_bf16(xr[0].x, xr[0].y); p[1] = cvt_pk_bf16(xr[0].z, xr[0].w);
            p[2] = cvt_pk_bf16(xr[1].x, xr[1].y); p[3] = cvt_pk_bf16(xr[1].z, xr[1].w);
            *(bf8*)&xs[xrow][xcol] = *(bf8*)p;
            #pragma unroll
            for (int it = 0; it < 6; ++it) {
                const int n = t + it * 256;
                *(bf8*)&wts[n >> 3][(n & 7) * 8] = wreg[it];
            }
        }
        __syncthreads();
        if (kc + 1 < C_DIM / 64) {
            const int kb = (kc + 1) * 64;
            xr[0] = *(const float4*)&x[(r0 + xrow) * C_DIM + kb + xcol];
            xr[1] = *(const float4*)&x[(r0 + xrow) * C_DIM + kb + xcol + 4];
            #pragma unroll
            for (int it = 0; it < 6; ++it) {
                const int n = t + it * 256;
                wreg[it] = *(const bf8*)&wtg[(size_t)(n >> 3) * C_DIM + kb + (n & 7) * 8];
            }
        }
        #pragma unroll
        for (int ks = 0; ks < 2; ++ks) {
            const bf8 a0 = *(const bf8*)&xs[lid][ks * 32 + g * 8];
            const bf8 a1 = *(const bf8*)&xs[16 + lid][ks * 32 + g * 8];
            #pragma unroll
            for (int j = 0; j < 3; ++j) {
                const int ct = wave * 3 + j;
                const bf8 bb = *(const bf8*)&wts[ct * 16 + lid][ks * 32 + g * 8];
                acc[0][j] = __builtin_amdgcn_mfma_f32_16x16x32_bf16(a0, bb, acc[0][j], 0, 0, 0);
                acc[1][j] = __builtin_amdgcn_mfma_f32_16x16x32_bf16(a1, bb, acc[1][j], 0, 0, 0);
            }
        }
    }

    #pragma unroll
    for (int rt = 0; rt < 2; ++rt)
        #pragma unroll
        for (int j = 0; j < 3; ++j) {
            const int ct = wave * 3 + j;
            const int m  = ct >> 2, lc = (ct & 3) * 16 + lid;
            ushort* dst = (m == 0) ? qo : (m == 1) ? ko : vo;
            const float sc = (m == 0) ? SCALE2 : 1.f;
            #pragma unroll
            for (int r = 0; r < 4; ++r) {
                const size_t row = r0 + rt * 16 + 4 * g + r;
                dst[row * H_DIM + lc] = f2bf(acc[rt][j][r] * sc);
            }
        }
}

// ---------------------------------------------------------------------------
// Split-K flash on 32x32x16 MFMA, QBLK=256 (8 waves x 32 rows), KBLK=64.
// Fixed-shift softmax (P = 2^S2). Grid (nslots, 16, 4), 512 threads.
// Partial O stored as bf16. Body = R14-verbatim otherwise.
// ---------------------------------------------------------------------------
__global__ __launch_bounds__(512) void flash_mfma_kernel(
    const ushort* __restrict__ q, const ushort* __restrict__ k,
    const ushort* __restrict__ v, ushort* __restrict__ pO,
    float* __restrict__ pl, float* __restrict__ out,
    int S, int nslots, int direct)
{
    const int qt  = 15 - blockIdx.y;         // heavy q-tiles first
    const int c   = blockIdx.x;
    const int ntk = 4 * qt + 4;              // 64-key tiles for this q-tile
    const int kt_begin = c * S;
    const int kt_end   = min((c + 1) * S, ntk);
    if (kt_begin >= kt_end) return;          // inactive chunk (block-uniform)

    __shared__ ushort ks[64][KP];            // K tile, row-major [key][h]
    __shared__ ushort vt[64][KP];            // V^T tile: vt[h][key]
    __shared__ float  lsh[8][32];            // per-wave l for epilogue

    const int t    = threadIdx.x;
    const int lane = t & 63, wave = t >> 6;  // wave 0..7
    const int l31  = lane & 31, hi = lane >> 5;
    const int b    = blockIdx.z;
    const int qrow0 = qt * 256 + wave * 32;  // wave's first q row
    const int ktw_max = (qrow0 + 31) >> 6;   // last k-tile with any valid key
    const size_t base = (size_t)b * T_DIM * H_DIM;

    // Q B-frags: lane holds Q2[qrow0+l31][kk*16 + hi*8 .. +8), kk=0..3
    bf8 qf[4];
    {
        const size_t qoff = base + (size_t)(qrow0 + l31) * H_DIM + hi * 8;
        #pragma unroll
        for (int kk = 0; kk < 4; ++kk)
            qf[kk] = *(const bf8*)&q[qoff + kk * 16];
    }

    f32x16 oa0 = {}, oa1 = {};           // O[q rows][h = l31 / 32+l31]
    float l_run = 0.f;                   // per-lane denominator, q = l31

    // staging coords (512 threads):
    //   K: row t>>3 (0..63), 8-col group (t&7)*8 -> 1 bf8/thread
    //   V: keys (vj, vj+1) x 4 h-cols vc -> 2x 8B loads, 4 b32 transpose writes
    const int krow = t >> 3, kc8 = (t & 7) * 8;
    const int vj = (t & 31) * 2, vc = (t >> 5) * 4;
    bf8 krg;
    bf4 vr0, vr1;
    {
        const int kg = kt_begin * 64;
        krg = *(const bf8*)&k[base + (size_t)(kg + krow) * H_DIM + kc8];
        vr0 = *(const bf4*)&v[base + (size_t)(kg + vj) * H_DIM + vc];
        vr1 = *(const bf4*)&v[base + (size_t)(kg + vj + 1) * H_DIM + vc];
    }

    #define BUILD_PA(dst, sv, bofs) do {                                   \
        uint a0_ = cvt_pk_bf16(sv[(bofs)+0], sv[(bofs)+1]);                \
        uint b0_ = cvt_pk_bf16(sv[(bofs)+4], sv[(bofs)+5]);                \
        uint a1_ = cvt_pk_bf16(sv[(bofs)+2], sv[(bofs)+3]);                \
        uint b1_ = cvt_pk_bf16(sv[(bofs)+6], sv[(bofs)+7]);                \
        permswapu(a0_, b0_); permswapu(a1_, b1_);                          \
        dst = frag_from(a0_, a1_, b0_, b1_);                               \
    } while (0)

    for (int kt64 = kt_begin; kt64 < kt_end; ++kt64) {
        __syncthreads();                 // prev tile LDS reads done
        *(bf8*)&ks[krow][kc8] = krg;
        #pragma unroll
        for (int i = 0; i < 4; ++i) {    // vt[h=vc+i][keys vj, vj+1]
            const uint pk = (uint)(ushort)vr0[i] | ((uint)(ushort)vr1[i] << 16);
            *(uint*)&vt[vc + i][vj] = pk;
        }
        __syncthreads();                 // tile ready
        if (kt64 + 1 < kt_end) {         // prefetch next tile (full iter cover)
            const int kg = (kt64 + 1) * 64;
            krg = *(const bf8*)&k[base + (size_t)(kg + krow) * H_DIM + kc8];
            vr0 = *(const bf4*)&v[base + (size_t)(kg + vj) * H_DIM + vc];
            vr1 = *(const bf4*)&v[base + (size_t)(kg + vj + 1) * H_DIM + vc];
        }
        if (kt64 > ktw_max) continue;    // fully masked for this wave (uniform)

        // S2^T = mfma(K, Q2): lane q=l31, keys per C-layout regs
        f32x16 st0 = {}, st1 = {};
        #pragma unroll
        for (int kk = 0; kk < 4; ++kk) {
            const bf8 kfa = *(const bf8*)&ks[l31][kk * 16 + hi * 8];
            st0 = __builtin_amdgcn_mfma_f32_32x32x16_bf16(kfa, qf[kk], st0, 0, 0, 0);
        }
        #pragma unroll
        for (int kk = 0; kk < 4; ++kk) {
            const bf8 kfb = *(const bf8*)&ks[32 + l31][kk * 16 + hi * 8];
            st1 = __builtin_amdgcn_mfma_f32_32x32x16_bf16(kfb, qf[kk], st1, 0, 0, 0);
        }

        // causal mask (near-diagonal tiles only)
        if (kt64 * 64 + 63 > qrow0) {
            const int qg  = qrow0 + l31;
            const int kb0 = kt64 * 64 + 4 * hi;
            #pragma unroll
            for (int r = 0; r < 16; ++r) {
                const int key0 = kb0 + (r & 3) + 8 * (r >> 2);
                if (key0 > qg)      st0[r] = -1e30f;  // 2^-1e30 -> 0 exactly
                if (key0 + 32 > qg) st1[r] = -1e30f;
            }
        }

        // fixed-shift softmax: P = 2^S2 (exact; scale cancels in num/denom)
        #pragma unroll
        for (int r = 0; r < 16; ++r) st0[r] = fast_exp2(st0[r]);
        #pragma unroll
        for (int r = 0; r < 16; ++r) st1[r] = fast_exp2(st1[r]);

        // tree sum of 32 P values + one permlane swap
        float sr[8];
        #pragma unroll
        for (int r = 0; r < 8; ++r)
            sr[r] = (st0[r] + st0[r + 8]) + (st1[r] + st1[r + 8]);
        #pragma unroll
        for (int off = 4; off > 0; off >>= 1)
            #pragma unroll
            for (int r = 0; r < 4; ++r)
                if (r < off) sr[r] += sr[r + off];
        float ls = sr[0];
        { float la = ls, lb = ls; permswapf(la, lb); ls = la + lb; }
        l_run += ls;

        // P -> bf16 A-frags fully in-register (cvt_pk + permlane32_swap)
        bf8 pa[4];
        BUILD_PA(pa[0], st0, 0);
        BUILD_PA(pa[1], st0, 8);
        BUILD_PA(pa[2], st1, 0);
        BUILD_PA(pa[3], st1, 8);

        // PV: A = P[q][key], B = V^T from vt; O[q][h]
        #pragma unroll
        for (int kk = 0; kk < 4; ++kk) {
            const bf8 vb0 = *(const bf8*)&vt[l31][kk * 16 + hi * 8];
            const bf8 vb1 = *(const bf8*)&vt[32 + l31][kk * 16 + hi * 8];
            oa0 = __builtin_amdgcn_mfma_f32_32x32x16_bf16(pa[kk], vb0, oa0, 0, 0, 0);
            oa1 = __builtin_amdgcn_mfma_f32_32x32x16_bf16(pa[kk], vb1, oa1, 0, 0, 0);
        }
    }
    #undef BUILD_PA

    if (direct) {
        if (lane < 32) lsh[wave][l31] = l_run;
        #pragma unroll
        for (int j = 0; j < 4; ++j) {
            const float4 lv = *(const float4*)&lsh[wave][8 * j + 4 * hi];
            const float iv[4] = {1.f / lv.x, 1.f / lv.y, 1.f / lv.z, 1.f / lv.w};
            #pragma unroll
            for (int rr = 0; rr < 4; ++rr) {
                const size_t rowoff = base + (size_t)(qrow0 + 8 * j + 4 * hi + rr) * H_DIM;
                out[rowoff + l31]      = oa0[4 * j + rr] * iv[rr];
                out[rowoff + 32 + l31] = oa1[4 * j + rr] * iv[rr];
            }
        }
    } else {
        const size_t u = ((size_t)b * 16 + qt) * nslots + c;
        ushort* po = pO + u * 16384;         // 256 rows x 64 cols, bf16
        #pragma unroll
        for (int j = 0; j < 4; ++j)
            #pragma unroll
            for (int rr = 0; rr < 4; ++rr) {
                const int row = wave * 32 + 8 * j + 4 * hi + rr;
                po[(size_t)row * 64 + l31]      = f2bf(oa0[4 * j + rr]);
                po[(size_t)row * 64 + 32 + l31] = f2bf(oa1[4 * j + rr]);
            }
        if (lane < 32)
            pl[u * 256 + wave * 32 + l31] = l_run;
    }
}

// ---------------------------------------------------------------------------
// Combine partials: out = (sum_c pO_c) / (sum_c l_c), pO in bf16.
// Grid (32, 4): blockIdx.x = 128-row half of a 256-row q-tile.
// ---------------------------------------------------------------------------
__global__ __launch_bounds__(256) void combine_kernel(
    const ushort* __restrict__ pO, const float* __restrict__ pl,
    float* __restrict__ out, int S, int nslots)
{
    const int qt2 = blockIdx.x, b = blockIdx.y;
    const int qt = qt2 >> 1, half = qt2 & 1;
    const int ntk = 4 * qt + 4;
    const int nch = min(nslots, (ntk + S - 1) / S);
    const int t = threadIdx.x;
    const int row = half * 128 + (t >> 1), seg = (t & 1) * 32;
    const size_t u0 = ((size_t)b * 16 + qt) * nslots;

    float L = 0.f;
    float oacc[32] = {};
    for (int cc = 0; cc < nch; ++cc) {
        L += pl[(u0 + cc) * 256 + row];
        const ushort* pb = pO + (u0 + cc) * 16384 + (size_t)row * 64 + seg;
        #pragma unroll
        for (int jj = 0; jj < 4; ++jj) {
            const bf8 pv = *(const bf8*)&pb[jj * 8];
            #pragma unroll
            for (int i = 0; i < 8; ++i)
                oacc[jj * 8 + i] += bf2f((ushort)pv[i]);
        }
    }
    const float inv = 1.f / L;
    const size_t ob = (size_t)b * T_DIM * H_DIM + (size_t)(qt * 256 + row) * H_DIM + seg;
    #pragma unroll
    for (int jj = 0; jj < 8; ++jj) {
        float4 r;
        r.x = oacc[jj * 4 + 0] * inv; r.y = oacc[jj * 4 + 1] * inv;
        r.z = oacc[jj * 4 + 2] * inv; r.w = oacc[jj * 4 + 3] * inv;
        *(float4*)&out[ob + jj * 4] = r;
    }
}

// ---------------------------------------------------------------------------
extern "C" void kernel_launch(void* const* d_in, const int* in_sizes, int n_in,
                              void* d_out, int out_size, void* d_ws, size_t ws_size,
                              hipStream_t stream)
{
    const float* x  = (const float*)d_in[0];
    const float* Wq = (const float*)d_in[1];
    const float* Wk = (const float*)d_in[2];
    const float* Wv = (const float*)d_in[3];
    float* out = (float*)d_out;

    const size_t MB = 1u << 20;
    char* ws = (char*)d_ws;
    ushort* qb  = (ushort*)(ws);            // 2MB
    ushort* kb  = (ushort*)(ws + 2 * MB);   // 2MB
    ushort* vb  = (ushort*)(ws + 4 * MB);   // 2MB
    ushort* wtg = (ushort*)(ws + 6 * MB);   // 384KB
    ushort* pO  = (ushort*)(ws + 7 * MB);   // bf16 partials

    // tiers in 64-key tiles (max 64 per 256-row q-tile); ws measured ~268MB
    int nslots, S;
    if      (ws_size >= 80 * MB) { nslots = 32; S = 2; }   // pO 64MB + pl 2MB
    else if (ws_size >= 48 * MB) { nslots = 16; S = 4; }   // pO 32MB + pl 1MB
    else if (ws_size >= 28 * MB) { nslots = 8;  S = 8; }
    else                         { nslots = 1;  S = 64; }
    const int direct = (nslots == 1);
    float* pl = (float*)(ws + 7 * MB +
                         (size_t)B_DIM * 16 * nslots * 16384 * sizeof(ushort));

    hipLaunchKernelGGL(wt_kernel, dim3(96), dim3(256), 0, stream, Wq, Wk, Wv, wtg);
    hipLaunchKernelGGL(qkv_mfma_kernel, dim3((B_DIM * T_DIM) / 32), dim3(256),
                       0, stream, x, wtg, qb, kb, vb);
    hipLaunchKernelGGL(flash_mfma_kernel, dim3(nslots, T_DIM / 256, B_DIM), dim3(512),
                       0, stream, qb, kb, vb, pO, pl, out, S, nslots, direct);
    if (!direct)
        hipLaunchKernelGGL(combine_kernel, dim3(32, B_DIM), dim3(256),
                           0, stream, pO, pl, out, S, nslots);
}

// Round 18
// 73.822 us; speedup vs baseline: 1.1287x; 1.1287x over previous
//
#include <hip/hip_runtime.h>
#include <hip/hip_bf16.h>

// Single causal attention head. B=4, T=4096, C=1024, H=64, fp32 in/out.
// R17 = R14 (best, 71.05us: flash QBLK=256/KBLK=64 fixed-shift, fp32 pO,
// nslots=16/S=4) with qkv restructured to SINGLE barrier per chunk:
// double-buffered LDS (xs/wts x2) + 2-deep named register pipeline (A/B).
// Loads issue at iter top, drain at the iter-end barrier -> ~2x latency cover.

#define B_DIM 4
#define T_DIM 4096
#define C_DIM 1024
#define H_DIM 64
#define SCALE2 0.0450842066f  // log2(e)/32 : base-2 domain folded into q
#define KP 72                 // LDS stride (elems): 144B rows, 16B-aligned

typedef __attribute__((ext_vector_type(8))) short bf8;      // 8 bf16
typedef __attribute__((ext_vector_type(4))) short bf4;      // 4 bf16 (8B)
typedef __attribute__((ext_vector_type(4))) float f32x4;    // 16x16 acc
typedef __attribute__((ext_vector_type(16))) float f32x16;  // 32x32 acc

__device__ __forceinline__ float fast_exp2(float f) {
    return __builtin_amdgcn_exp2f(f);   // v_exp_f32 (base-2)
}
__device__ __forceinline__ ushort f2bf(float f) {
    union { float f; uint u; } x; x.f = f;
    const uint u = x.u;
    return (ushort)((u + 0x7FFFu + ((u >> 16) & 1u)) >> 16);  // RNE
}
__device__ __forceinline__ uint cvt_pk_bf16(float lo, float hi) {
    uint r;
    asm("v_cvt_pk_bf16_f32 %0, %1, %2" : "=v"(r) : "v"(lo), "v"(hi));
    return r;
}
__device__ __forceinline__ void permswapf(float& a, float& b) {
    asm volatile("v_permlane32_swap_b32 %0, %1" : "+v"(a), "+v"(b));
}
__device__ __forceinline__ void permswapu(uint& a, uint& b) {
    asm volatile("v_permlane32_swap_b32 %0, %1" : "+v"(a), "+v"(b));
}
__device__ __forceinline__ bf8 frag_from(uint w0, uint w1, uint w2, uint w3) {
    union { uint u[4]; bf8 f; } x;
    x.u[0] = w0; x.u[1] = w1; x.u[2] = w2; x.u[3] = w3;
    return x.f;
}

// ---------------------------------------------------------------------------
// W^T pre-pass: wtg[col][k], col 0..191 = (Wq|Wk|Wv) columns, bf16.
// ---------------------------------------------------------------------------
__global__ __launch_bounds__(256) void wt_kernel(
    const float* __restrict__ Wq, const float* __restrict__ Wk,
    const float* __restrict__ Wv, ushort* __restrict__ wtg)
{
    const int id  = blockIdx.x * 256 + threadIdx.x;  // 24576 total
    const int col = id >> 7;
    const int k8  = (id & 127) * 8;
    const int m   = col >> 6, lc = col & 63;
    const float* W = (m == 0) ? Wq : (m == 1) ? Wk : Wv;
    ushort o[8];
    #pragma unroll
    for (int i = 0; i < 8; ++i)
        o[i] = f2bf(W[(size_t)(k8 + i) * H_DIM + lc]);
    *(bf8*)&wtg[(size_t)col * C_DIM + k8] = *(bf8*)o;
}

// ---------------------------------------------------------------------------
// QKV projection, single-barrier pipeline. Block = 32 rows x 192 cols,
// 4 waves x 3 col-subtiles; K-chunks of 64. LDS double-buffered; register
// sets A/B ping-pong (2-deep). Every load crosses exactly one barrier
// before use; drain cover = full iteration. Grid 512.
// ---------------------------------------------------------------------------
__global__ __launch_bounds__(256) void qkv_mfma_kernel(
    const float* __restrict__ x, const ushort* __restrict__ wtg,
    ushort* __restrict__ qo, ushort* __restrict__ ko, ushort* __restrict__ vo)
{
    __shared__ ushort xs0[32][KP], xs1[32][KP];
    __shared__ ushort wts0[192][KP], wts1[192][KP];
    const int t    = threadIdx.x;
    const int lane = t & 63, wave = t >> 6;
    const int g    = lane >> 4, lid = lane & 15;
    const size_t r0 = (size_t)blockIdx.x * 32;

    f32x4 acc[2][3] = {};

    const int xrow = t >> 3, xcol = (t & 7) * 8;   // x stage: 32x64, 1 bf8/thr
    float4 xrA[2], xrB[2];
    bf8 wrA[6], wrB[6];

    #define LOAD_SET(xr_, wr_, kc_) do {                                      \
        xr_[0] = *(const float4*)&x[(r0 + xrow) * C_DIM + (kc_) * 64 + xcol]; \
        xr_[1] = *(const float4*)&x[(r0 + xrow) * C_DIM + (kc_) * 64 + xcol + 4]; \
        _Pragma("unroll")                                                     \
        for (int it = 0; it < 6; ++it) {                                      \
            const int n = t + it * 256;                                       \
            wr_[it] = *(const bf8*)&wtg[(size_t)(n >> 3) * C_DIM +            \
                                        (kc_) * 64 + (n & 7) * 8];            \
        }                                                                     \
    } while (0)

    #define WRITE_SET(xs_, wts_, xr_, wr_) do {                               \
        uint p_[4];                                                           \
        p_[0] = cvt_pk_bf16(xr_[0].x, xr_[0].y);                              \
        p_[1] = cvt_pk_bf16(xr_[0].z, xr_[0].w);                              \
        p_[2] = cvt_pk_bf16(xr_[1].x, xr_[1].y);                              \
        p_[3] = cvt_pk_bf16(xr_[1].z, xr_[1].w);                              \
        *(bf8*)&xs_[xrow][xcol] = *(bf8*)p_;                                  \
        _Pragma("unroll")                                                     \
        for (int it = 0; it < 6; ++it) {                                      \
            const int n = t + it * 256;                                       \
            *(bf8*)&wts_[n >> 3][(n & 7) * 8] = wr_[it];                      \
        }                                                                     \
    } while (0)

    #define MFMA_STEP(xs_, wts_) do {                                         \
        _Pragma("unroll")                                                     \
        for (int ks = 0; ks < 2; ++ks) {                                      \
            const bf8 a0 = *(const bf8*)&xs_[lid][ks * 32 + g * 8];           \
            const bf8 a1 = *(const bf8*)&xs_[16 + lid][ks * 32 + g * 8];      \
            _Pragma("unroll")                                                 \
            for (int j = 0; j < 3; ++j) {                                     \
                const bf8 bb = *(const bf8*)&wts_[(wave * 3 + j) * 16 + lid][ks * 32 + g * 8]; \
                acc[0][j] = __builtin_amdgcn_mfma_f32_16x16x32_bf16(a0, bb, acc[0][j], 0, 0, 0); \
                acc[1][j] = __builtin_amdgcn_mfma_f32_16x16x32_bf16(a1, bb, acc[1][j], 0, 0, 0); \
            }                                                                 \
        }                                                                     \
    } while (0)

    // prologue: A <- chunk 0; write buf0; B <- chunk 1; barrier
    LOAD_SET(xrA, wrA, 0);
    WRITE_SET(xs0, wts0, xrA, wrA);      // waits A (prologue only)
    LOAD_SET(xrB, wrB, 1);
    __syncthreads();                     // buf0 ready (drains B; one-time)

    for (int kc = 0; kc < C_DIM / 64; kc += 2) {
        // even: compute kc from buf0; stage kc+1 (B, landed) into buf1
        if (kc + 2 < C_DIM / 64) LOAD_SET(xrA, wrA, kc + 2);   // issue at top
        MFMA_STEP(xs0, wts0);
        WRITE_SET(xs1, wts1, xrB, wrB);
        __syncthreads();                 // buf1 ready; drains A (full-iter cover)

        // odd: compute kc+1 from buf1; stage kc+2 (A, landed) into buf0
        if (kc + 3 < C_DIM / 64) LOAD_SET(xrB, wrB, kc + 3);
        MFMA_STEP(xs1, wts1);
        if (kc + 2 < C_DIM / 64) WRITE_SET(xs0, wts0, xrA, wrA);
        __syncthreads();                 // buf0 ready; drains B
    }
    #undef MFMA_STEP
    #undef WRITE_SET
    #undef LOAD_SET

    #pragma unroll
    for (int rt = 0; rt < 2; ++rt)
        #pragma unroll
        for (int j = 0; j < 3; ++j) {
            const int ct = wave * 3 + j;
            const int m  = ct >> 2, lc = (ct & 3) * 16 + lid;
            ushort* dst = (m == 0) ? qo : (m == 1) ? ko : vo;
            const float sc = (m == 0) ? SCALE2 : 1.f;
            #pragma unroll
            for (int r = 0; r < 4; ++r) {
                const size_t row = r0 + rt * 16 + 4 * g + r;
                dst[row * H_DIM + lc] = f2bf(acc[rt][j][r] * sc);
            }
        }
}

// ---------------------------------------------------------------------------
// Split-K flash on 32x32x16 MFMA (R14 verbatim). QBLK=256 (8 waves x 32
// rows), KBLK=64, fixed-shift softmax (P = 2^S2). Grid (nslots, 16, 4).
// ---------------------------------------------------------------------------
__global__ __launch_bounds__(512) void flash_mfma_kernel(
    const ushort* __restrict__ q, const ushort* __restrict__ k,
    const ushort* __restrict__ v, float* __restrict__ pO,
    float* __restrict__ pl, float* __restrict__ out,
    int S, int nslots, int direct)
{
    const int qt  = 15 - blockIdx.y;         // heavy q-tiles first
    const int c   = blockIdx.x;
    const int ntk = 4 * qt + 4;              // 64-key tiles for this q-tile
    const int kt_begin = c * S;
    const int kt_end   = min((c + 1) * S, ntk);
    if (kt_begin >= kt_end) return;          // inactive chunk (block-uniform)

    __shared__ ushort ks[64][KP];            // K tile, row-major [key][h]
    __shared__ ushort vt[64][KP];            // V^T tile: vt[h][key]
    __shared__ float  lsh[8][32];            // per-wave l for epilogue

    const int t    = threadIdx.x;
    const int lane = t & 63, wave = t >> 6;  // wave 0..7
    const int l31  = lane & 31, hi = lane >> 5;
    const int b    = blockIdx.z;
    const int qrow0 = qt * 256 + wave * 32;  // wave's first q row
    const int ktw_max = (qrow0 + 31) >> 6;   // last k-tile with any valid key
    const size_t base = (size_t)b * T_DIM * H_DIM;

    // Q B-frags: lane holds Q2[qrow0+l31][kk*16 + hi*8 .. +8), kk=0..3
    bf8 qf[4];
    {
        const size_t qoff = base + (size_t)(qrow0 + l31) * H_DIM + hi * 8;
        #pragma unroll
        for (int kk = 0; kk < 4; ++kk)
            qf[kk] = *(const bf8*)&q[qoff + kk * 16];
    }

    f32x16 oa0 = {}, oa1 = {};           // O[q rows][h = l31 / 32+l31]
    float l_run = 0.f;                   // per-lane denominator, q = l31

    // staging coords (512 threads):
    //   K: row t>>3 (0..63), 8-col group (t&7)*8 -> 1 bf8/thread
    //   V: keys (vj, vj+1) x 4 h-cols vc -> 2x 8B loads, 4 b32 transpose writes
    const int krow = t >> 3, kc8 = (t & 7) * 8;
    const int vj = (t & 31) * 2, vc = (t >> 5) * 4;
    bf8 krg;
    bf4 vr0, vr1;
    {
        const int kg = kt_begin * 64;
        krg = *(const bf8*)&k[base + (size_t)(kg + krow) * H_DIM + kc8];
        vr0 = *(const bf4*)&v[base + (size_t)(kg + vj) * H_DIM + vc];
        vr1 = *(const bf4*)&v[base + (size_t)(kg + vj + 1) * H_DIM + vc];
    }

    #define BUILD_PA(dst, sv, bofs) do {                                   \
        uint a0_ = cvt_pk_bf16(sv[(bofs)+0], sv[(bofs)+1]);                \
        uint b0_ = cvt_pk_bf16(sv[(bofs)+4], sv[(bofs)+5]);                \
        uint a1_ = cvt_pk_bf16(sv[(bofs)+2], sv[(bofs)+3]);                \
        uint b1_ = cvt_pk_bf16(sv[(bofs)+6], sv[(bofs)+7]);                \
        permswapu(a0_, b0_); permswapu(a1_, b1_);                          \
        dst = frag_from(a0_, a1_, b0_, b1_);                               \
    } while (0)

    for (int kt64 = kt_begin; kt64 < kt_end; ++kt64) {
        __syncthreads();                 // prev tile LDS reads done
        *(bf8*)&ks[krow][kc8] = krg;
        #pragma unroll
        for (int i = 0; i < 4; ++i) {    // vt[h=vc+i][keys vj, vj+1]
            const uint pk = (uint)(ushort)vr0[i] | ((uint)(ushort)vr1[i] << 16);
            *(uint*)&vt[vc + i][vj] = pk;
        }
        __syncthreads();                 // tile ready
        if (kt64 + 1 < kt_end) {         // prefetch next tile (full iter cover)
            const int kg = (kt64 + 1) * 64;
            krg = *(const bf8*)&k[base + (size_t)(kg + krow) * H_DIM + kc8];
            vr0 = *(const bf4*)&v[base + (size_t)(kg + vj) * H_DIM + vc];
            vr1 = *(const bf4*)&v[base + (size_t)(kg + vj + 1) * H_DIM + vc];
        }
        if (kt64 > ktw_max) continue;    // fully masked for this wave (uniform)

        // S2^T = mfma(K, Q2): lane q=l31, keys per C-layout regs
        f32x16 st0 = {}, st1 = {};
        #pragma unroll
        for (int kk = 0; kk < 4; ++kk) {
            const bf8 kfa = *(const bf8*)&ks[l31][kk * 16 + hi * 8];
            st0 = __builtin_amdgcn_mfma_f32_32x32x16_bf16(kfa, qf[kk], st0, 0, 0, 0);
        }
        #pragma unroll
        for (int kk = 0; kk < 4; ++kk) {
            const bf8 kfb = *(const bf8*)&ks[32 + l31][kk * 16 + hi * 8];
            st1 = __builtin_amdgcn_mfma_f32_32x32x16_bf16(kfb, qf[kk], st1, 0, 0, 0);
        }

        // causal mask (near-diagonal tiles only)
        if (kt64 * 64 + 63 > qrow0) {
            const int qg  = qrow0 + l31;
            const int kb0 = kt64 * 64 + 4 * hi;
            #pragma unroll
            for (int r = 0; r < 16; ++r) {
                const int key0 = kb0 + (r & 3) + 8 * (r >> 2);
                if (key0 > qg)      st0[r] = -1e30f;  // 2^-1e30 -> 0 exactly
                if (key0 + 32 > qg) st1[r] = -1e30f;
            }
        }

        // fixed-shift softmax: P = 2^S2 (exact; scale cancels in num/denom)
        #pragma unroll
        for (int r = 0; r < 16; ++r) st0[r] = fast_exp2(st0[r]);
        #pragma unroll
        for (int r = 0; r < 16; ++r) st1[r] = fast_exp2(st1[r]);

        // tree sum of 32 P values + one permlane swap
        float sr[8];
        #pragma unroll
        for (int r = 0; r < 8; ++r)
            sr[r] = (st0[r] + st0[r + 8]) + (st1[r] + st1[r + 8]);
        #pragma unroll
        for (int off = 4; off > 0; off >>= 1)
            #pragma unroll
            for (int r = 0; r < 4; ++r)
                if (r < off) sr[r] += sr[r + off];
        float ls = sr[0];
        { float la = ls, lb = ls; permswapf(la, lb); ls = la + lb; }
        l_run += ls;

        // P -> bf16 A-frags fully in-register (cvt_pk + permlane32_swap)
        bf8 pa[4];
        BUILD_PA(pa[0], st0, 0);
        BUILD_PA(pa[1], st0, 8);
        BUILD_PA(pa[2], st1, 0);
        BUILD_PA(pa[3], st1, 8);

        // PV: A = P[q][key], B = V^T from vt; O[q][h]
        #pragma unroll
        for (int kk = 0; kk < 4; ++kk) {
            const bf8 vb0 = *(const bf8*)&vt[l31][kk * 16 + hi * 8];
            const bf8 vb1 = *(const bf8*)&vt[32 + l31][kk * 16 + hi * 8];
            oa0 = __builtin_amdgcn_mfma_f32_32x32x16_bf16(pa[kk], vb0, oa0, 0, 0, 0);
            oa1 = __builtin_amdgcn_mfma_f32_32x32x16_bf16(pa[kk], vb1, oa1, 0, 0, 0);
        }
    }
    #undef BUILD_PA

    if (direct) {
        if (lane < 32) lsh[wave][l31] = l_run;
        #pragma unroll
        for (int j = 0; j < 4; ++j) {
            const float4 lv = *(const float4*)&lsh[wave][8 * j + 4 * hi];
            const float iv[4] = {1.f / lv.x, 1.f / lv.y, 1.f / lv.z, 1.f / lv.w};
            #pragma unroll
            for (int rr = 0; rr < 4; ++rr) {
                const size_t rowoff = base + (size_t)(qrow0 + 8 * j + 4 * hi + rr) * H_DIM;
                out[rowoff + l31]      = oa0[4 * j + rr] * iv[rr];
                out[rowoff + 32 + l31] = oa1[4 * j + rr] * iv[rr];
            }
        }
    } else {
        const size_t u = ((size_t)b * 16 + qt) * nslots + c;
        float* po = pO + u * 16384;          // 256 rows x 64 cols
        #pragma unroll
        for (int j = 0; j < 4; ++j)
            #pragma unroll
            for (int rr = 0; rr < 4; ++rr) {
                const int row = wave * 32 + 8 * j + 4 * hi + rr;
                po[(size_t)row * 64 + l31]      = oa0[4 * j + rr];
                po[(size_t)row * 64 + 32 + l31] = oa1[4 * j + rr];
            }
        if (lane < 32)
            pl[u * 256 + wave * 32 + l31] = l_run;
    }
}

// ---------------------------------------------------------------------------
// Combine partials: out = (sum_c pO_c) / (sum_c l_c). Fixed shift -> plain
// sums. Grid (32, 4): blockIdx.x = 128-row half of a 256-row q-tile.
// ---------------------------------------------------------------------------
__global__ __launch_bounds__(256) void combine_kernel(
    const float* __restrict__ pO, const float* __restrict__ pl,
    float* __restrict__ out, int S, int nslots)
{
    const int qt2 = blockIdx.x, b = blockIdx.y;
    const int qt = qt2 >> 1, half = qt2 & 1;
    const int ntk = 4 * qt + 4;
    const int nch = min(nslots, (ntk + S - 1) / S);
    const int t = threadIdx.x;
    const int row = half * 128 + (t >> 1), seg = (t & 1) * 32;
    const size_t u0 = ((size_t)b * 16 + qt) * nslots;

    float L = 0.f;
    float4 o[8] = {};
    for (int cc = 0; cc < nch; ++cc) {
        L += pl[(u0 + cc) * 256 + row];
        #pragma unroll
        for (int j = 0; j < 8; ++j) {
            const float4 p = *(const float4*)&pO[(u0 + cc) * 16384 +
                                                 (size_t)row * 64 + seg + j * 4];
            o[j].x += p.x; o[j].y += p.y;
            o[j].z += p.z; o[j].w += p.w;
        }
    }
    const float inv = 1.f / L;
    const size_t ob = (size_t)b * T_DIM * H_DIM + (size_t)(qt * 256 + row) * H_DIM + seg;
    #pragma unroll
    for (int j = 0; j < 8; ++j) {
        float4 r;
        r.x = o[j].x * inv; r.y = o[j].y * inv;
        r.z = o[j].z * inv; r.w = o[j].w * inv;
        *(float4*)&out[ob + j * 4] = r;
    }
}

// ---------------------------------------------------------------------------
extern "C" void kernel_launch(void* const* d_in, const int* in_sizes, int n_in,
                              void* d_out, int out_size, void* d_ws, size_t ws_size,
                              hipStream_t stream)
{
    const float* x  = (const float*)d_in[0];
    const float* Wq = (const float*)d_in[1];
    const float* Wk = (const float*)d_in[2];
    const float* Wv = (const float*)d_in[3];
    float* out = (float*)d_out;

    const size_t MB = 1u << 20;
    char* ws = (char*)d_ws;
    ushort* qb  = (ushort*)(ws);            // 2MB
    ushort* kb  = (ushort*)(ws + 2 * MB);   // 2MB
    ushort* vb  = (ushort*)(ws + 4 * MB);   // 2MB
    ushort* wtg = (ushort*)(ws + 6 * MB);   // 384KB
    float*  pO  = (float*)(ws + 7 * MB);

    // tiers in 64-key tiles (max 64 per 256-row q-tile); ws measured ~268MB
    int nslots, S;
    if      (ws_size >= 80 * MB) { nslots = 16; S = 4; }
    else if (ws_size >= 48 * MB) { nslots = 8;  S = 8; }
    else if (ws_size >= 28 * MB) { nslots = 4;  S = 16; }
    else                         { nslots = 1;  S = 64; }
    const int direct = (nslots == 1);
    float* pl = pO + (size_t)B_DIM * 16 * nslots * 16384;

    hipLaunchKernelGGL(wt_kernel, dim3(96), dim3(256), 0, stream, Wq, Wk, Wv, wtg);
    hipLaunchKernelGGL(qkv_mfma_kernel, dim3((B_DIM * T_DIM) / 32), dim3(256),
                       0, stream, x, wtg, qb, kb, vb);
    hipLaunchKernelGGL(flash_mfma_kernel, dim3(nslots, T_DIM / 256, B_DIM), dim3(512),
                       0, stream, qb, kb, vb, pO, pl, out, S, nslots, direct);
    if (!direct)
        hipLaunchKernelGGL(combine_kernel, dim3(32, B_DIM), dim3(256),
                           0, stream, pO, pl, out, S, nslots);
}

// Round 19
// 73.128 us; speedup vs baseline: 1.1394x; 1.0095x over previous
//
#include <hip/hip_runtime.h>
#include <hip/hip_bf16.h>

// Single causal attention head. B=4, T=4096, C=1024, H=64, fp32 in/out.
// R18 = R14 base (qkv/wt/combine/tiers verbatim) + flash-only changes:
// (1) K/V LDS double-buffer, ONE barrier per 64-key iter (LDS 19.5->38KB is
//     free: occupancy is VGPR-limited at 2 blocks/CU),
// (2) s_setprio(1) around QK and PV MFMA clusters (T5).

#define B_DIM 4
#define T_DIM 4096
#define C_DIM 1024
#define H_DIM 64
#define SCALE2 0.0450842066f  // log2(e)/32 : base-2 domain folded into q
#define KP 72                 // LDS stride (elems): 144B rows, 16B-aligned

typedef __attribute__((ext_vector_type(8))) short bf8;      // 8 bf16
typedef __attribute__((ext_vector_type(4))) short bf4;      // 4 bf16 (8B)
typedef __attribute__((ext_vector_type(4))) float f32x4;    // 16x16 acc
typedef __attribute__((ext_vector_type(16))) float f32x16;  // 32x32 acc

__device__ __forceinline__ float fast_exp2(float f) {
    return __builtin_amdgcn_exp2f(f);   // v_exp_f32 (base-2)
}
__device__ __forceinline__ ushort f2bf(float f) {
    union { float f; uint u; } x; x.f = f;
    const uint u = x.u;
    return (ushort)((u + 0x7FFFu + ((u >> 16) & 1u)) >> 16);  // RNE
}
__device__ __forceinline__ uint cvt_pk_bf16(float lo, float hi) {
    uint r;
    asm("v_cvt_pk_bf16_f32 %0, %1, %2" : "=v"(r) : "v"(lo), "v"(hi));
    return r;
}
__device__ __forceinline__ void permswapf(float& a, float& b) {
    asm volatile("v_permlane32_swap_b32 %0, %1" : "+v"(a), "+v"(b));
}
__device__ __forceinline__ void permswapu(uint& a, uint& b) {
    asm volatile("v_permlane32_swap_b32 %0, %1" : "+v"(a), "+v"(b));
}
__device__ __forceinline__ bf8 frag_from(uint w0, uint w1, uint w2, uint w3) {
    union { uint u[4]; bf8 f; } x;
    x.u[0] = w0; x.u[1] = w1; x.u[2] = w2; x.u[3] = w3;
    return x.f;
}

// ---------------------------------------------------------------------------
// W^T pre-pass: wtg[col][k], col 0..191 = (Wq|Wk|Wv) columns, bf16.
// ---------------------------------------------------------------------------
__global__ __launch_bounds__(256) void wt_kernel(
    const float* __restrict__ Wq, const float* __restrict__ Wk,
    const float* __restrict__ Wv, ushort* __restrict__ wtg)
{
    const int id  = blockIdx.x * 256 + threadIdx.x;  // 24576 total
    const int col = id >> 7;
    const int k8  = (id & 127) * 8;
    const int m   = col >> 6, lc = col & 63;
    const float* W = (m == 0) ? Wq : (m == 1) ? Wk : Wv;
    ushort o[8];
    #pragma unroll
    for (int i = 0; i < 8; ++i)
        o[i] = f2bf(W[(size_t)(k8 + i) * H_DIM + lc]);
    *(bf8*)&wtg[(size_t)col * C_DIM + k8] = *(bf8*)o;
}

// ---------------------------------------------------------------------------
// QKV projection (R6 verbatim). Block = 32 rows x 192 cols, 4 waves x 3
// col-subtiles; K-chunks of 64 with reg-prefetch. Grid 512.
// ---------------------------------------------------------------------------
__global__ __launch_bounds__(256) void qkv_mfma_kernel(
    const float* __restrict__ x, const ushort* __restrict__ wtg,
    ushort* __restrict__ qo, ushort* __restrict__ ko, ushort* __restrict__ vo)
{
    __shared__ ushort xs[32][KP];
    __shared__ ushort wts[192][KP];
    const int t    = threadIdx.x;
    const int lane = t & 63, wave = t >> 6;
    const int g    = lane >> 4, lid = lane & 15;
    const size_t r0 = (size_t)blockIdx.x * 32;

    f32x4 acc[2][3] = {};

    const int xrow = t >> 3, xcol = (t & 7) * 8;   // x stage: 32x64
    float4 xr[2];
    bf8 wreg[6];

    xr[0] = *(const float4*)&x[(r0 + xrow) * C_DIM + xcol];
    xr[1] = *(const float4*)&x[(r0 + xrow) * C_DIM + xcol + 4];
    #pragma unroll
    for (int it = 0; it < 6; ++it) {
        const int n = t + it * 256;
        wreg[it] = *(const bf8*)&wtg[(size_t)(n >> 3) * C_DIM + (n & 7) * 8];
    }

    for (int kc = 0; kc < C_DIM / 64; ++kc) {
        __syncthreads();
        {
            uint p[4];
            p[0] = cvt_pk_bf16(xr[0].x, xr[0].y); p[1] = cvt_pk_bf16(xr[0].z, xr[0].w);
            p[2] = cvt_pk_bf16(xr[1].x, xr[1].y); p[3] = cvt_pk_bf16(xr[1].z, xr[1].w);
            *(bf8*)&xs[xrow][xcol] = *(bf8*)p;
            #pragma unroll
            for (int it = 0; it < 6; ++it) {
                const int n = t + it * 256;
                *(bf8*)&wts[n >> 3][(n & 7) * 8] = wreg[it];
            }
        }
        __syncthreads();
        if (kc + 1 < C_DIM / 64) {
            const int kb = (kc + 1) * 64;
            xr[0] = *(const float4*)&x[(r0 + xrow) * C_DIM + kb + xcol];
            xr[1] = *(const float4*)&x[(r0 + xrow) * C_DIM + kb + xcol + 4];
            #pragma unroll
            for (int it = 0; it < 6; ++it) {
                const int n = t + it * 256;
                wreg[it] = *(const bf8*)&wtg[(size_t)(n >> 3) * C_DIM + kb + (n & 7) * 8];
            }
        }
        #pragma unroll
        for (int ks = 0; ks < 2; ++ks) {
            const bf8 a0 = *(const bf8*)&xs[lid][ks * 32 + g * 8];
            const bf8 a1 = *(const bf8*)&xs[16 + lid][ks * 32 + g * 8];
            #pragma unroll
            for (int j = 0; j < 3; ++j) {
                const int ct = wave * 3 + j;
                const bf8 bb = *(const bf8*)&wts[ct * 16 + lid][ks * 32 + g * 8];
                acc[0][j] = __builtin_amdgcn_mfma_f32_16x16x32_bf16(a0, bb, acc[0][j], 0, 0, 0);
                acc[1][j] = __builtin_amdgcn_mfma_f32_16x16x32_bf16(a1, bb, acc[1][j], 0, 0, 0);
            }
        }
    }

    #pragma unroll
    for (int rt = 0; rt < 2; ++rt)
        #pragma unroll
        for (int j = 0; j < 3; ++j) {
            const int ct = wave * 3 + j;
            const int m  = ct >> 2, lc = (ct & 3) * 16 + lid;
            ushort* dst = (m == 0) ? qo : (m == 1) ? ko : vo;
            const float sc = (m == 0) ? SCALE2 : 1.f;
            #pragma unroll
            for (int r = 0; r < 4; ++r) {
                const size_t row = r0 + rt * 16 + 4 * g + r;
                dst[row * H_DIM + lc] = f2bf(acc[rt][j][r] * sc);
            }
        }
}

// ---------------------------------------------------------------------------
// Split-K flash on 32x32x16 MFMA. QBLK=256 (8 waves x 32 rows), KBLK=64,
// fixed-shift softmax (P = 2^S2). K/V LDS DOUBLE-buffered, ONE barrier per
// iter; loads issue at iter top (compute-phase cover before the write's
// vmcnt wait). s_setprio(1) around MFMA clusters. Grid (nslots, 16, 4).
// ---------------------------------------------------------------------------
__global__ __launch_bounds__(512) void flash_mfma_kernel(
    const ushort* __restrict__ q, const ushort* __restrict__ k,
    const ushort* __restrict__ v, float* __restrict__ pO,
    float* __restrict__ pl, float* __restrict__ out,
    int S, int nslots, int direct)
{
    const int qt  = 15 - blockIdx.y;         // heavy q-tiles first
    const int c   = blockIdx.x;
    const int ntk = 4 * qt + 4;              // 64-key tiles for this q-tile
    const int kt_begin = c * S;
    const int kt_end   = min((c + 1) * S, ntk);
    if (kt_begin >= kt_end) return;          // inactive chunk (block-uniform)

    __shared__ ushort ks[2][64][KP];         // K tiles, row-major [key][h]
    __shared__ ushort vt[2][64][KP];         // V^T tiles: vt[h][key]
    __shared__ float  lsh[8][32];            // per-wave l for epilogue

    const int t    = threadIdx.x;
    const int lane = t & 63, wave = t >> 6;  // wave 0..7
    const int l31  = lane & 31, hi = lane >> 5;
    const int b    = blockIdx.z;
    const int qrow0 = qt * 256 + wave * 32;  // wave's first q row
    const int ktw_max = (qrow0 + 31) >> 6;   // last k-tile with any valid key
    const size_t base = (size_t)b * T_DIM * H_DIM;

    // Q B-frags: lane holds Q2[qrow0+l31][kk*16 + hi*8 .. +8), kk=0..3
    bf8 qf[4];
    {
        const size_t qoff = base + (size_t)(qrow0 + l31) * H_DIM + hi * 8;
        #pragma unroll
        for (int kk = 0; kk < 4; ++kk)
            qf[kk] = *(const bf8*)&q[qoff + kk * 16];
    }

    f32x16 oa0 = {}, oa1 = {};           // O[q rows][h = l31 / 32+l31]
    float l_run = 0.f;                   // per-lane denominator, q = l31

    // staging coords (512 threads):
    //   K: row t>>3 (0..63), 8-col group (t&7)*8 -> 1 bf8/thread
    //   V: keys (vj, vj+1) x 4 h-cols vc -> 2x 8B loads, 4 b32 transpose writes
    const int krow = t >> 3, kc8 = (t & 7) * 8;
    const int vj = (t & 31) * 2, vc = (t >> 5) * 4;
    bf8 krg;
    bf4 vr0, vr1;

    #define LOAD_STAGE(kt_) do {                                              \
        const int kg_ = (kt_) * 64;                                           \
        krg = *(const bf8*)&k[base + (size_t)(kg_ + krow) * H_DIM + kc8];     \
        vr0 = *(const bf4*)&v[base + (size_t)(kg_ + vj) * H_DIM + vc];        \
        vr1 = *(const bf4*)&v[base + (size_t)(kg_ + vj + 1) * H_DIM + vc];    \
    } while (0)

    #define WRITE_STAGE(buf_) do {                                            \
        *(bf8*)&ks[buf_][krow][kc8] = krg;                                    \
        _Pragma("unroll")                                                     \
        for (int i = 0; i < 4; ++i) {                                         \
            const uint pk = (uint)(ushort)vr0[i] | ((uint)(ushort)vr1[i] << 16); \
            *(uint*)&vt[buf_][vc + i][vj] = pk;                               \
        }                                                                     \
    } while (0)

    #define BUILD_PA(dst, sv, bofs) do {                                   \
        uint a0_ = cvt_pk_bf16(sv[(bofs)+0], sv[(bofs)+1]);                \
        uint b0_ = cvt_pk_bf16(sv[(bofs)+4], sv[(bofs)+5]);                \
        uint a1_ = cvt_pk_bf16(sv[(bofs)+2], sv[(bofs)+3]);                \
        uint b1_ = cvt_pk_bf16(sv[(bofs)+6], sv[(bofs)+7]);                \
        permswapu(a0_, b0_); permswapu(a1_, b1_);                          \
        dst = frag_from(a0_, a1_, b0_, b1_);                               \
    } while (0)

    // prologue: stage first tile into buf0
    LOAD_STAGE(kt_begin);
    WRITE_STAGE(0);
    __syncthreads();                     // buf0 ready
    int cur = 0;

    for (int kt64 = kt_begin; kt64 < kt_end; ++kt64) {
        const bool more = (kt64 + 1 < kt_end);
        if (more) LOAD_STAGE(kt64 + 1);  // issue at top; lands under compute

        if (kt64 <= ktw_max) {           // compute (skip if fully masked)
            // S2^T = mfma(K, Q2): lane q=l31, keys per C-layout regs
            f32x16 st0 = {}, st1 = {};
            __builtin_amdgcn_s_setprio(1);
            #pragma unroll
            for (int kk = 0; kk < 4; ++kk) {
                const bf8 kfa = *(const bf8*)&ks[cur][l31][kk * 16 + hi * 8];
                st0 = __builtin_amdgcn_mfma_f32_32x32x16_bf16(kfa, qf[kk], st0, 0, 0, 0);
            }
            #pragma unroll
            for (int kk = 0; kk < 4; ++kk) {
                const bf8 kfb = *(const bf8*)&ks[cur][32 + l31][kk * 16 + hi * 8];
                st1 = __builtin_amdgcn_mfma_f32_32x32x16_bf16(kfb, qf[kk], st1, 0, 0, 0);
            }
            __builtin_amdgcn_s_setprio(0);

            // causal mask (near-diagonal tiles only)
            if (kt64 * 64 + 63 > qrow0) {
                const int qg  = qrow0 + l31;
                const int kb0 = kt64 * 64 + 4 * hi;
                #pragma unroll
                for (int r = 0; r < 16; ++r) {
                    const int key0 = kb0 + (r & 3) + 8 * (r >> 2);
                    if (key0 > qg)      st0[r] = -1e30f;  // 2^-1e30 -> 0
                    if (key0 + 32 > qg) st1[r] = -1e30f;
                }
            }

            // fixed-shift softmax: P = 2^S2
            #pragma unroll
            for (int r = 0; r < 16; ++r) st0[r] = fast_exp2(st0[r]);
            #pragma unroll
            for (int r = 0; r < 16; ++r) st1[r] = fast_exp2(st1[r]);

            // tree sum of 32 P values + one permlane swap
            float sr[8];
            #pragma unroll
            for (int r = 0; r < 8; ++r)
                sr[r] = (st0[r] + st0[r + 8]) + (st1[r] + st1[r + 8]);
            #pragma unroll
            for (int off = 4; off > 0; off >>= 1)
                #pragma unroll
                for (int r = 0; r < 4; ++r)
                    if (r < off) sr[r] += sr[r + off];
            float ls = sr[0];
            { float la = ls, lb = ls; permswapf(la, lb); ls = la + lb; }
            l_run += ls;

            // P -> bf16 A-frags fully in-register (cvt_pk + permlane32_swap)
            bf8 pa[4];
            BUILD_PA(pa[0], st0, 0);
            BUILD_PA(pa[1], st0, 8);
            BUILD_PA(pa[2], st1, 0);
            BUILD_PA(pa[3], st1, 8);

            // PV: A = P[q][key], B = V^T from vt; O[q][h]
            __builtin_amdgcn_s_setprio(1);
            #pragma unroll
            for (int kk = 0; kk < 4; ++kk) {
                const bf8 vb0 = *(const bf8*)&vt[cur][l31][kk * 16 + hi * 8];
                const bf8 vb1 = *(const bf8*)&vt[cur][32 + l31][kk * 16 + hi * 8];
                oa0 = __builtin_amdgcn_mfma_f32_32x32x16_bf16(pa[kk], vb0, oa0, 0, 0, 0);
                oa1 = __builtin_amdgcn_mfma_f32_32x32x16_bf16(pa[kk], vb1, oa1, 0, 0, 0);
            }
            __builtin_amdgcn_s_setprio(0);
        }

        if (more) WRITE_STAGE(cur ^ 1);  // vmcnt wait covered by compute phase
        __syncthreads();                 // next buffer ready; prev reads done
        cur ^= 1;
    }
    #undef BUILD_PA
    #undef WRITE_STAGE
    #undef LOAD_STAGE

    if (direct) {
        if (lane < 32) lsh[wave][l31] = l_run;
        #pragma unroll
        for (int j = 0; j < 4; ++j) {
            const float4 lv = *(const float4*)&lsh[wave][8 * j + 4 * hi];
            const float iv[4] = {1.f / lv.x, 1.f / lv.y, 1.f / lv.z, 1.f / lv.w};
            #pragma unroll
            for (int rr = 0; rr < 4; ++rr) {
                const size_t rowoff = base + (size_t)(qrow0 + 8 * j + 4 * hi + rr) * H_DIM;
                out[rowoff + l31]      = oa0[4 * j + rr] * iv[rr];
                out[rowoff + 32 + l31] = oa1[4 * j + rr] * iv[rr];
            }
        }
    } else {
        const size_t u = ((size_t)b * 16 + qt) * nslots + c;
        float* po = pO + u * 16384;          // 256 rows x 64 cols
        #pragma unroll
        for (int j = 0; j < 4; ++j)
            #pragma unroll
            for (int rr = 0; rr < 4; ++rr) {
                const int row = wave * 32 + 8 * j + 4 * hi + rr;
                po[(size_t)row * 64 + l31]      = oa0[4 * j + rr];
                po[(size_t)row * 64 + 32 + l31] = oa1[4 * j + rr];
            }
        if (lane < 32)
            pl[u * 256 + wave * 32 + l31] = l_run;
    }
}

// ---------------------------------------------------------------------------
// Combine partials: out = (sum_c pO_c) / (sum_c l_c). Fixed shift -> plain
// sums. Grid (32, 4): blockIdx.x = 128-row half of a 256-row q-tile.
// ---------------------------------------------------------------------------
__global__ __launch_bounds__(256) void combine_kernel(
    const float* __restrict__ pO, const float* __restrict__ pl,
    float* __restrict__ out, int S, int nslots)
{
    const int qt2 = blockIdx.x, b = blockIdx.y;
    const int qt = qt2 >> 1, half = qt2 & 1;
    const int ntk = 4 * qt + 4;
    const int nch = min(nslots, (ntk + S - 1) / S);
    const int t = threadIdx.x;
    const int row = half * 128 + (t >> 1), seg = (t & 1) * 32;
    const size_t u0 = ((size_t)b * 16 + qt) * nslots;

    float L = 0.f;
    float4 o[8] = {};
    for (int cc = 0; cc < nch; ++cc) {
        L += pl[(u0 + cc) * 256 + row];
        #pragma unroll
        for (int j = 0; j < 8; ++j) {
            const float4 p = *(const float4*)&pO[(u0 + cc) * 16384 +
                                                 (size_t)row * 64 + seg + j * 4];
            o[j].x += p.x; o[j].y += p.y;
            o[j].z += p.z; o[j].w += p.w;
        }
    }
    const float inv = 1.f / L;
    const size_t ob = (size_t)b * T_DIM * H_DIM + (size_t)(qt * 256 + row) * H_DIM + seg;
    #pragma unroll
    for (int j = 0; j < 8; ++j) {
        float4 r;
        r.x = o[j].x * inv; r.y = o[j].y * inv;
        r.z = o[j].z * inv; r.w = o[j].w * inv;
        *(float4*)&out[ob + j * 4] = r;
    }
}

// ---------------------------------------------------------------------------
extern "C" void kernel_launch(void* const* d_in, const int* in_sizes, int n_in,
                              void* d_out, int out_size, void* d_ws, size_t ws_size,
                              hipStream_t stream)
{
    const float* x  = (const float*)d_in[0];
    const float* Wq = (const float*)d_in[1];
    const float* Wk = (const float*)d_in[2];
    const float* Wv = (const float*)d_in[3];
    float* out = (float*)d_out;

    const size_t MB = 1u << 20;
    char* ws = (char*)d_ws;
    ushort* qb  = (ushort*)(ws);            // 2MB
    ushort* kb  = (ushort*)(ws + 2 * MB);   // 2MB
    ushort* vb  = (ushort*)(ws + 4 * MB);   // 2MB
    ushort* wtg = (ushort*)(ws + 6 * MB);   // 384KB
    float*  pO  = (float*)(ws + 7 * MB);

    // tiers in 64-key tiles (max 64 per 256-row q-tile); ws measured ~268MB
    int nslots, S;
    if      (ws_size >= 80 * MB) { nslots = 16; S = 4; }
    else if (ws_size >= 48 * MB) { nslots = 8;  S = 8; }
    else if (ws_size >= 28 * MB) { nslots = 4;  S = 16; }
    else                         { nslots = 1;  S = 64; }
    const int direct = (nslots == 1);
    float* pl = pO + (size_t)B_DIM * 16 * nslots * 16384;

    hipLaunchKernelGGL(wt_kernel, dim3(96), dim3(256), 0, stream, Wq, Wk, Wv, wtg);
    hipLaunchKernelGGL(qkv_mfma_kernel, dim3((B_DIM * T_DIM) / 32), dim3(256),
                       0, stream, x, wtg, qb, kb, vb);
    hipLaunchKernelGGL(flash_mfma_kernel, dim3(nslots, T_DIM / 256, B_DIM), dim3(512),
                       0, stream, qb, kb, vb, pO, pl, out, S, nslots, direct);
    if (!direct)
        hipLaunchKernelGGL(combine_kernel, dim3(32, B_DIM), dim3(256),
                           0, stream, pO, pl, out, S, nslots);
}

// Round 20
// 70.873 us; speedup vs baseline: 1.1757x; 1.0318x over previous
//
#include <hip/hip_runtime.h>
#include <hip/hip_bf16.h>

// Single causal attention head. B=4, T=4096, C=1024, H=64, fp32 in/out.
// R19 = R14 byte-identical (best measured, 71.05us) + ONE delta:
// s_setprio(1)/(0) around flash's QK and PV MFMA clusters (T5, isolated).

#define B_DIM 4
#define T_DIM 4096
#define C_DIM 1024
#define H_DIM 64
#define SCALE2 0.0450842066f  // log2(e)/32 : base-2 domain folded into q
#define KP 72                 // LDS stride (elems): 144B rows, 16B-aligned

typedef __attribute__((ext_vector_type(8))) short bf8;      // 8 bf16
typedef __attribute__((ext_vector_type(4))) short bf4;      // 4 bf16 (8B)
typedef __attribute__((ext_vector_type(4))) float f32x4;    // 16x16 acc
typedef __attribute__((ext_vector_type(16))) float f32x16;  // 32x32 acc

__device__ __forceinline__ float fast_exp2(float f) {
    return __builtin_amdgcn_exp2f(f);   // v_exp_f32 (base-2)
}
__device__ __forceinline__ ushort f2bf(float f) {
    union { float f; uint u; } x; x.f = f;
    const uint u = x.u;
    return (ushort)((u + 0x7FFFu + ((u >> 16) & 1u)) >> 16);  // RNE
}
__device__ __forceinline__ uint cvt_pk_bf16(float lo, float hi) {
    uint r;
    asm("v_cvt_pk_bf16_f32 %0, %1, %2" : "=v"(r) : "v"(lo), "v"(hi));
    return r;
}
__device__ __forceinline__ void permswapf(float& a, float& b) {
    asm volatile("v_permlane32_swap_b32 %0, %1" : "+v"(a), "+v"(b));
}
__device__ __forceinline__ void permswapu(uint& a, uint& b) {
    asm volatile("v_permlane32_swap_b32 %0, %1" : "+v"(a), "+v"(b));
}
__device__ __forceinline__ bf8 frag_from(uint w0, uint w1, uint w2, uint w3) {
    union { uint u[4]; bf8 f; } x;
    x.u[0] = w0; x.u[1] = w1; x.u[2] = w2; x.u[3] = w3;
    return x.f;
}

// ---------------------------------------------------------------------------
// W^T pre-pass: wtg[col][k], col 0..191 = (Wq|Wk|Wv) columns, bf16.
// ---------------------------------------------------------------------------
__global__ __launch_bounds__(256) void wt_kernel(
    const float* __restrict__ Wq, const float* __restrict__ Wk,
    const float* __restrict__ Wv, ushort* __restrict__ wtg)
{
    const int id  = blockIdx.x * 256 + threadIdx.x;  // 24576 total
    const int col = id >> 7;
    const int k8  = (id & 127) * 8;
    const int m   = col >> 6, lc = col & 63;
    const float* W = (m == 0) ? Wq : (m == 1) ? Wk : Wv;
    ushort o[8];
    #pragma unroll
    for (int i = 0; i < 8; ++i)
        o[i] = f2bf(W[(size_t)(k8 + i) * H_DIM + lc]);
    *(bf8*)&wtg[(size_t)col * C_DIM + k8] = *(bf8*)o;
}

// ---------------------------------------------------------------------------
// QKV projection (R6 verbatim). Block = 32 rows x 192 cols, 4 waves x 3
// col-subtiles; K-chunks of 64 with reg-prefetch. Grid 512.
// ---------------------------------------------------------------------------
__global__ __launch_bounds__(256) void qkv_mfma_kernel(
    const float* __restrict__ x, const ushort* __restrict__ wtg,
    ushort* __restrict__ qo, ushort* __restrict__ ko, ushort* __restrict__ vo)
{
    __shared__ ushort xs[32][KP];
    __shared__ ushort wts[192][KP];
    const int t    = threadIdx.x;
    const int lane = t & 63, wave = t >> 6;
    const int g    = lane >> 4, lid = lane & 15;
    const size_t r0 = (size_t)blockIdx.x * 32;

    f32x4 acc[2][3] = {};

    const int xrow = t >> 3, xcol = (t & 7) * 8;   // x stage: 32x64
    float4 xr[2];
    bf8 wreg[6];

    xr[0] = *(const float4*)&x[(r0 + xrow) * C_DIM + xcol];
    xr[1] = *(const float4*)&x[(r0 + xrow) * C_DIM + xcol + 4];
    #pragma unroll
    for (int it = 0; it < 6; ++it) {
        const int n = t + it * 256;
        wreg[it] = *(const bf8*)&wtg[(size_t)(n >> 3) * C_DIM + (n & 7) * 8];
    }

    for (int kc = 0; kc < C_DIM / 64; ++kc) {
        __syncthreads();
        {
            uint p[4];
            p[0] = cvt_pk_bf16(xr[0].x, xr[0].y); p[1] = cvt_pk_bf16(xr[0].z, xr[0].w);
            p[2] = cvt_pk_bf16(xr[1].x, xr[1].y); p[3] = cvt_pk_bf16(xr[1].z, xr[1].w);
            *(bf8*)&xs[xrow][xcol] = *(bf8*)p;
            #pragma unroll
            for (int it = 0; it < 6; ++it) {
                const int n = t + it * 256;
                *(bf8*)&wts[n >> 3][(n & 7) * 8] = wreg[it];
            }
        }
        __syncthreads();
        if (kc + 1 < C_DIM / 64) {
            const int kb = (kc + 1) * 64;
            xr[0] = *(const float4*)&x[(r0 + xrow) * C_DIM + kb + xcol];
            xr[1] = *(const float4*)&x[(r0 + xrow) * C_DIM + kb + xcol + 4];
            #pragma unroll
            for (int it = 0; it < 6; ++it) {
                const int n = t + it * 256;
                wreg[it] = *(const bf8*)&wtg[(size_t)(n >> 3) * C_DIM + kb + (n & 7) * 8];
            }
        }
        #pragma unroll
        for (int ks = 0; ks < 2; ++ks) {
            const bf8 a0 = *(const bf8*)&xs[lid][ks * 32 + g * 8];
            const bf8 a1 = *(const bf8*)&xs[16 + lid][ks * 32 + g * 8];
            #pragma unroll
            for (int j = 0; j < 3; ++j) {
                const int ct = wave * 3 + j;
                const bf8 bb = *(const bf8*)&wts[ct * 16 + lid][ks * 32 + g * 8];
                acc[0][j] = __builtin_amdgcn_mfma_f32_16x16x32_bf16(a0, bb, acc[0][j], 0, 0, 0);
                acc[1][j] = __builtin_amdgcn_mfma_f32_16x16x32_bf16(a1, bb, acc[1][j], 0, 0, 0);
            }
        }
    }

    #pragma unroll
    for (int rt = 0; rt < 2; ++rt)
        #pragma unroll
        for (int j = 0; j < 3; ++j) {
            const int ct = wave * 3 + j;
            const int m  = ct >> 2, lc = (ct & 3) * 16 + lid;
            ushort* dst = (m == 0) ? qo : (m == 1) ? ko : vo;
            const float sc = (m == 0) ? SCALE2 : 1.f;
            #pragma unroll
            for (int r = 0; r < 4; ++r) {
                const size_t row = r0 + rt * 16 + 4 * g + r;
                dst[row * H_DIM + lc] = f2bf(acc[rt][j][r] * sc);
            }
        }
}

// ---------------------------------------------------------------------------
// Split-K flash on 32x32x16 MFMA (R14 structure). QBLK=256 (8 waves x 32
// rows), KBLK=64, fixed-shift softmax (P = 2^S2). Grid (nslots, 16, 4),
// 512 threads. Single LDS buffer, 2 barriers/iter, reg-prefetch after the
// ready-barrier. ONLY delta vs R14: s_setprio around MFMA clusters.
// ---------------------------------------------------------------------------
__global__ __launch_bounds__(512) void flash_mfma_kernel(
    const ushort* __restrict__ q, const ushort* __restrict__ k,
    const ushort* __restrict__ v, float* __restrict__ pO,
    float* __restrict__ pl, float* __restrict__ out,
    int S, int nslots, int direct)
{
    const int qt  = 15 - blockIdx.y;         // heavy q-tiles first
    const int c   = blockIdx.x;
    const int ntk = 4 * qt + 4;              // 64-key tiles for this q-tile
    const int kt_begin = c * S;
    const int kt_end   = min((c + 1) * S, ntk);
    if (kt_begin >= kt_end) return;          // inactive chunk (block-uniform)

    __shared__ ushort ks[64][KP];            // K tile, row-major [key][h]
    __shared__ ushort vt[64][KP];            // V^T tile: vt[h][key]
    __shared__ float  lsh[8][32];            // per-wave l for epilogue

    const int t    = threadIdx.x;
    const int lane = t & 63, wave = t >> 6;  // wave 0..7
    const int l31  = lane & 31, hi = lane >> 5;
    const int b    = blockIdx.z;
    const int qrow0 = qt * 256 + wave * 32;  // wave's first q row
    const int ktw_max = (qrow0 + 31) >> 6;   // last k-tile with any valid key
    const size_t base = (size_t)b * T_DIM * H_DIM;

    // Q B-frags: lane holds Q2[qrow0+l31][kk*16 + hi*8 .. +8), kk=0..3
    bf8 qf[4];
    {
        const size_t qoff = base + (size_t)(qrow0 + l31) * H_DIM + hi * 8;
        #pragma unroll
        for (int kk = 0; kk < 4; ++kk)
            qf[kk] = *(const bf8*)&q[qoff + kk * 16];
    }

    f32x16 oa0 = {}, oa1 = {};           // O[q rows][h = l31 / 32+l31]
    float l_run = 0.f;                   // per-lane denominator, q = l31

    // staging coords (512 threads):
    //   K: row t>>3 (0..63), 8-col group (t&7)*8 -> 1 bf8/thread
    //   V: keys (vj, vj+1) x 4 h-cols vc -> 2x 8B loads, 4 b32 transpose writes
    const int krow = t >> 3, kc8 = (t & 7) * 8;
    const int vj = (t & 31) * 2, vc = (t >> 5) * 4;
    bf8 krg;
    bf4 vr0, vr1;
    {
        const int kg = kt_begin * 64;
        krg = *(const bf8*)&k[base + (size_t)(kg + krow) * H_DIM + kc8];
        vr0 = *(const bf4*)&v[base + (size_t)(kg + vj) * H_DIM + vc];
        vr1 = *(const bf4*)&v[base + (size_t)(kg + vj + 1) * H_DIM + vc];
    }

    #define BUILD_PA(dst, sv, bofs) do {                                   \
        uint a0_ = cvt_pk_bf16(sv[(bofs)+0], sv[(bofs)+1]);                \
        uint b0_ = cvt_pk_bf16(sv[(bofs)+4], sv[(bofs)+5]);                \
        uint a1_ = cvt_pk_bf16(sv[(bofs)+2], sv[(bofs)+3]);                \
        uint b1_ = cvt_pk_bf16(sv[(bofs)+6], sv[(bofs)+7]);                \
        permswapu(a0_, b0_); permswapu(a1_, b1_);                          \
        dst = frag_from(a0_, a1_, b0_, b1_);                               \
    } while (0)

    for (int kt64 = kt_begin; kt64 < kt_end; ++kt64) {
        __syncthreads();                 // prev tile LDS reads done
        *(bf8*)&ks[krow][kc8] = krg;
        #pragma unroll
        for (int i = 0; i < 4; ++i) {    // vt[h=vc+i][keys vj, vj+1]
            const uint pk = (uint)(ushort)vr0[i] | ((uint)(ushort)vr1[i] << 16);
            *(uint*)&vt[vc + i][vj] = pk;
        }
        __syncthreads();                 // tile ready
        if (kt64 + 1 < kt_end) {         // prefetch next tile (full iter cover)
            const int kg = (kt64 + 1) * 64;
            krg = *(const bf8*)&k[base + (size_t)(kg + krow) * H_DIM + kc8];
            vr0 = *(const bf4*)&v[base + (size_t)(kg + vj) * H_DIM + vc];
            vr1 = *(const bf4*)&v[base + (size_t)(kg + vj + 1) * H_DIM + vc];
        }
        if (kt64 > ktw_max) continue;    // fully masked for this wave (uniform)

        // S2^T = mfma(K, Q2): lane q=l31, keys per C-layout regs
        f32x16 st0 = {}, st1 = {};
        __builtin_amdgcn_s_setprio(1);
        #pragma unroll
        for (int kk = 0; kk < 4; ++kk) {
            const bf8 kfa = *(const bf8*)&ks[l31][kk * 16 + hi * 8];
            st0 = __builtin_amdgcn_mfma_f32_32x32x16_bf16(kfa, qf[kk], st0, 0, 0, 0);
        }
        #pragma unroll
        for (int kk = 0; kk < 4; ++kk) {
            const bf8 kfb = *(const bf8*)&ks[32 + l31][kk * 16 + hi * 8];
            st1 = __builtin_amdgcn_mfma_f32_32x32x16_bf16(kfb, qf[kk], st1, 0, 0, 0);
        }
        __builtin_amdgcn_s_setprio(0);

        // causal mask (near-diagonal tiles only)
        if (kt64 * 64 + 63 > qrow0) {
            const int qg  = qrow0 + l31;
            const int kb0 = kt64 * 64 + 4 * hi;
            #pragma unroll
            for (int r = 0; r < 16; ++r) {
                const int key0 = kb0 + (r & 3) + 8 * (r >> 2);
                if (key0 > qg)      st0[r] = -1e30f;  // 2^-1e30 -> 0 exactly
                if (key0 + 32 > qg) st1[r] = -1e30f;
            }
        }

        // fixed-shift softmax: P = 2^S2 (exact; scale cancels in num/denom)
        #pragma unroll
        for (int r = 0; r < 16; ++r) st0[r] = fast_exp2(st0[r]);
        #pragma unroll
        for (int r = 0; r < 16; ++r) st1[r] = fast_exp2(st1[r]);

        // tree sum of 32 P values + one permlane swap
        float sr[8];
        #pragma unroll
        for (int r = 0; r < 8; ++r)
            sr[r] = (st0[r] + st0[r + 8]) + (st1[r] + st1[r + 8]);
        #pragma unroll
        for (int off = 4; off > 0; off >>= 1)
            #pragma unroll
            for (int r = 0; r < 4; ++r)
                if (r < off) sr[r] += sr[r + off];
        float ls = sr[0];
        { float la = ls, lb = ls; permswapf(la, lb); ls = la + lb; }
        l_run += ls;

        // P -> bf16 A-frags fully in-register (cvt_pk + permlane32_swap)
        bf8 pa[4];
        BUILD_PA(pa[0], st0, 0);
        BUILD_PA(pa[1], st0, 8);
        BUILD_PA(pa[2], st1, 0);
        BUILD_PA(pa[3], st1, 8);

        // PV: A = P[q][key], B = V^T from vt; O[q][h]
        __builtin_amdgcn_s_setprio(1);
        #pragma unroll
        for (int kk = 0; kk < 4; ++kk) {
            const bf8 vb0 = *(const bf8*)&vt[l31][kk * 16 + hi * 8];
            const bf8 vb1 = *(const bf8*)&vt[32 + l31][kk * 16 + hi * 8];
            oa0 = __builtin_amdgcn_mfma_f32_32x32x16_bf16(pa[kk], vb0, oa0, 0, 0, 0);
            oa1 = __builtin_amdgcn_mfma_f32_32x32x16_bf16(pa[kk], vb1, oa1, 0, 0, 0);
        }
        __builtin_amdgcn_s_setprio(0);
    }
    #undef BUILD_PA

    if (direct) {
        if (lane < 32) lsh[wave][l31] = l_run;
        #pragma unroll
        for (int j = 0; j < 4; ++j) {
            const float4 lv = *(const float4*)&lsh[wave][8 * j + 4 * hi];
            const float iv[4] = {1.f / lv.x, 1.f / lv.y, 1.f / lv.z, 1.f / lv.w};
            #pragma unroll
            for (int rr = 0; rr < 4; ++rr) {
                const size_t rowoff = base + (size_t)(qrow0 + 8 * j + 4 * hi + rr) * H_DIM;
                out[rowoff + l31]      = oa0[4 * j + rr] * iv[rr];
                out[rowoff + 32 + l31] = oa1[4 * j + rr] * iv[rr];
            }
        }
    } else {
        const size_t u = ((size_t)b * 16 + qt) * nslots + c;
        float* po = pO + u * 16384;          // 256 rows x 64 cols
        #pragma unroll
        for (int j = 0; j < 4; ++j)
            #pragma unroll
            for (int rr = 0; rr < 4; ++rr) {
                const int row = wave * 32 + 8 * j + 4 * hi + rr;
                po[(size_t)row * 64 + l31]      = oa0[4 * j + rr];
                po[(size_t)row * 64 + 32 + l31] = oa1[4 * j + rr];
            }
        if (lane < 32)
            pl[u * 256 + wave * 32 + l31] = l_run;
    }
}

// ---------------------------------------------------------------------------
// Combine partials: out = (sum_c pO_c) / (sum_c l_c). Fixed shift -> plain
// sums. Grid (32, 4): blockIdx.x = 128-row half of a 256-row q-tile.
// ---------------------------------------------------------------------------
__global__ __launch_bounds__(256) void combine_kernel(
    const float* __restrict__ pO, const float* __restrict__ pl,
    float* __restrict__ out, int S, int nslots)
{
    const int qt2 = blockIdx.x, b = blockIdx.y;
    const int qt = qt2 >> 1, half = qt2 & 1;
    const int ntk = 4 * qt + 4;
    const int nch = min(nslots, (ntk + S - 1) / S);
    const int t = threadIdx.x;
    const int row = half * 128 + (t >> 1), seg = (t & 1) * 32;
    const size_t u0 = ((size_t)b * 16 + qt) * nslots;

    float L = 0.f;
    float4 o[8] = {};
    for (int cc = 0; cc < nch; ++cc) {
        L += pl[(u0 + cc) * 256 + row];
        #pragma unroll
        for (int j = 0; j < 8; ++j) {
            const float4 p = *(const float4*)&pO[(u0 + cc) * 16384 +
                                                 (size_t)row * 64 + seg + j * 4];
            o[j].x += p.x; o[j].y += p.y;
            o[j].z += p.z; o[j].w += p.w;
        }
    }
    const float inv = 1.f / L;
    const size_t ob = (size_t)b * T_DIM * H_DIM + (size_t)(qt * 256 + row) * H_DIM + seg;
    #pragma unroll
    for (int j = 0; j < 8; ++j) {
        float4 r;
        r.x = o[j].x * inv; r.y = o[j].y * inv;
        r.z = o[j].z * inv; r.w = o[j].w * inv;
        *(float4*)&out[ob + j * 4] = r;
    }
}

// ---------------------------------------------------------------------------
extern "C" void kernel_launch(void* const* d_in, const int* in_sizes, int n_in,
                              void* d_out, int out_size, void* d_ws, size_t ws_size,
                              hipStream_t stream)
{
    const float* x  = (const float*)d_in[0];
    const float* Wq = (const float*)d_in[1];
    const float* Wk = (const float*)d_in[2];
    const float* Wv = (const float*)d_in[3];
    float* out = (float*)d_out;

    const size_t MB = 1u << 20;
    char* ws = (char*)d_ws;
    ushort* qb  = (ushort*)(ws);            // 2MB
    ushort* kb  = (ushort*)(ws + 2 * MB);   // 2MB
    ushort* vb  = (ushort*)(ws + 4 * MB);   // 2MB
    ushort* wtg = (ushort*)(ws + 6 * MB);   // 384KB
    float*  pO  = (float*)(ws + 7 * MB);

    // tiers in 64-key tiles (max 64 per 256-row q-tile); ws measured ~268MB
    int nslots, S;
    if      (ws_size >= 80 * MB) { nslots = 16; S = 4; }
    else if (ws_size >= 48 * MB) { nslots = 8;  S = 8; }
    else if (ws_size >= 28 * MB) { nslots = 4;  S = 16; }
    else                         { nslots = 1;  S = 64; }
    const int direct = (nslots == 1);
    float* pl = pO + (size_t)B_DIM * 16 * nslots * 16384;

    hipLaunchKernelGGL(wt_kernel, dim3(96), dim3(256), 0, stream, Wq, Wk, Wv, wtg);
    hipLaunchKernelGGL(qkv_mfma_kernel, dim3((B_DIM * T_DIM) / 32), dim3(256),
                       0, stream, x, wtg, qb, kb, vb);
    hipLaunchKernelGGL(flash_mfma_kernel, dim3(nslots, T_DIM / 256, B_DIM), dim3(512),
                       0, stream, qb, kb, vb, pO, pl, out, S, nslots, direct);
    if (!direct)
        hipLaunchKernelGGL(combine_kernel, dim3(32, B_DIM), dim3(256),
                           0, stream, pO, pl, out, S, nslots);
}